// Round 13
// baseline (267.063 us; speedup 1.0000x reference)
//
#include <hip/hip_runtime.h>
#include <cstdint>

#define NEXP 8
#define TOPK 2
#define NTOK 4096
#define NSLOT (NTOK * TOPK)   // 8192
#define CAP 1280              // expert capacity
#define DM 2048               // d_model == hidden
#define EC (NEXP * CAP)       // 10240 binned rows
#define KB4 1024              // bytes per K=2048 fp4 row
#define INV64 0.015625f       // weight pre-scale compensation (w quantized x64)

typedef __bf16 bf16x8 __attribute__((ext_vector_type(8)));
typedef float  f32x4  __attribute__((ext_vector_type(4)));
typedef int    i32x4  __attribute__((ext_vector_type(4)));
typedef int    i32x8  __attribute__((ext_vector_type(8)));

typedef const void __attribute__((address_space(1))) gvoid;
typedef void __attribute__((address_space(3))) lvoid;

__device__ __forceinline__ void gld16(const void* g, void* l) {
  __builtin_amdgcn_global_load_lds((gvoid*)(uintptr_t)g, (lvoid*)(uintptr_t)l,
                                   16, 0, 0);
}

// pack 4 f32 -> 4 fp8 e4m3 bytes (OCP on gfx950)
__device__ __forceinline__ unsigned fp8x4(float a, float b, float c, float d) {
  int v = __builtin_amdgcn_cvt_pk_fp8_f32(a, b, 0, false);
  v = __builtin_amdgcn_cvt_pk_fp8_f32(c, d, v, true);
  return (unsigned)v;
}
__device__ __forceinline__ unsigned char fp8one(float a) {
  return (unsigned char)(__builtin_amdgcn_cvt_pk_fp8_f32(a, a, 0, false) & 0xff);
}

// fp32 -> fp4 e2m1 nibble, round-to-nearest. Values {0,.5,1,1.5,2,3,4,6}.
__device__ __forceinline__ unsigned qfp4(float x) {
  float a = fabsf(x);
  unsigned s = (__float_as_uint(x) >> 28) & 8u;     // sign -> nibble bit3
  unsigned r = (a < 0.25f) ? 0u : (a < 0.75f) ? 1u : (a < 1.25f) ? 2u
             : (a < 1.75f) ? 3u : (a < 2.5f)  ? 4u : (a < 3.5f)  ? 5u
             : (a < 5.0f)  ? 6u : 7u;
  return s | r;
}

// ---------------------------------------------------------------- routing
__global__ void route_k(const int* __restrict__ eidx, int* __restrict__ row_token,
                        int* __restrict__ slot_dest, int* __restrict__ mcount,
                        float* __restrict__ out) {
  __shared__ int lh[256][NEXP];
  int tid = threadIdx.x;
  for (int i = tid; i < EC; i += 256) row_token[i] = -1;
#pragma unroll
  for (int e = 0; e < NEXP; ++e) lh[tid][e] = 0;
  __syncthreads();
  int base = tid * 32;
  for (int j = 0; j < 32; ++j) lh[tid][eidx[base + j]]++;
  __syncthreads();
  if (tid < NEXP) {
    int run = 0;
    for (int i = 0; i < 256; ++i) { int t = lh[i][tid]; lh[i][tid] = run; run += t; }
    mcount[tid] = run < CAP ? run : CAP;
    out[(size_t)NTOK * DM + tid] = (float)run;
  }
  __syncthreads();
  for (int j = 0; j < 32; ++j) {
    int t = base + j;
    int e = eidx[t];
    int r = lh[tid][e]++;
    if (r < CAP) { int dst = e * CAP + r; slot_dest[t] = dst; row_token[dst] = t >> 1; }
    else slot_dest[t] = -1;
  }
}

// -------------- device body: one 64x64 fp32 -> fp4(x64) transpose tile
// dst layout [E][N][K/2] nibble-packed (low nibble = even k).
__device__ __forceinline__ void transT_tile(const float* __restrict__ w,
                                            unsigned char* __restrict__ wT4,
                                            int e, int n0, int k0, char* smem) {
  float (*t)[69] = (float (*)[69])smem;
  const float* src = w + ((size_t)e << 22) + (size_t)k0 * DM + n0;
  unsigned char* dst = wT4 + ((size_t)e * DM + n0) * KB4 + (k0 >> 1);
  int c4 = (threadIdx.x & 15) * 4, r0 = threadIdx.x >> 4;   // 16 rows/sweep
#pragma unroll
  for (int p = 0; p < 4; ++p) {
    int r = p * 16 + r0;
    float4 v = *(const float4*)(src + (size_t)r * DM + c4);
    t[r][c4 + 0] = v.x; t[r][c4 + 1] = v.y; t[r][c4 + 2] = v.z; t[r][c4 + 3] = v.w;
  }
  __syncthreads();
  int j = threadIdx.x & 7, rr0 = threadIdx.x >> 3;          // 32 rows/sweep
#pragma unroll
  for (int q = 0; q < 2; ++q) {
    int rr = q * 32 + rr0;
    unsigned p = 0;
#pragma unroll
    for (int i = 0; i < 8; ++i)
      p |= qfp4(t[j * 8 + i][rr] * 64.f) << (4 * i);
    *(unsigned*)(dst + (size_t)rr * KB4 + j * 4) = p;       // 4B stores
  }
}

// ------------- prep: transT(w1) + transT(w3) + gather, one HBM-bound launch
__global__ __launch_bounds__(256)
void prep_k(const float* __restrict__ w1, const float* __restrict__ w3,
            unsigned char* __restrict__ wT1, unsigned char* __restrict__ wT3,
            const float* __restrict__ x, const int* __restrict__ row_token,
            unsigned char* __restrict__ xg) {
  __shared__ __align__(16) char smem[64 * 69 * 4];
  int bid = blockIdx.x;
  if (bid < 16384) {
    const float* w = (bid & 8192) ? w3 : w1;
    unsigned char* wT = (bid & 8192) ? wT3 : wT1;
    int rem = bid & 8191;
    int e = rem >> 10, t = rem & 1023;
    transT_tile(w, wT, e, (t & 31) * 64, (t >> 5) * 64, smem);
  } else {
    int rbase = (bid - 16384) * 8;
    int c = threadIdx.x * 8;
#pragma unroll 1
    for (int i = 0; i < 8; ++i) {
      int r = rbase + i;
      int tok = row_token[r];
      uint2 o;
      if (tok >= 0) {
        const float* src = x + (size_t)tok * DM + c;
        float4 a = *(const float4*)src;
        float4 b = *(const float4*)(src + 4);
        o.x = fp8x4(a.x, a.y, a.z, a.w);
        o.y = fp8x4(b.x, b.y, b.z, b.w);
      } else { o.x = 0u; o.y = 0u; }
      *(uint2*)(xg + (size_t)r * DM + c) = o;
    }
  }
}

// ---------------------------------------------- fused SwiGLU dual-B GEMM
// Mixed-format MFMA: A = fp8 e4m3 (cbsz=0), B = fp4 e2m1 x64 (blgp=4), unit
// MX scales; acc compensated by 1/64 in epilogue. 128x128 tile, BK=128,
// 4 waves, single-buffer 2-barrier loop (structure locked, R7-proven).
// B tiles: 128 rows x 128B covering TWO K-steps (staged every other ks) ->
// identical conflict-free chunk^(r&7) geometry as fp8 (m136 2-way = free).
// A frag = 2 b128 (32 k-bytes); B frag = 1 b128 (32 k-nibbles), data in low
// 4 VGPRs of the 8-reg operand. k-linear both sides (write-side-compensated
// swizzle) -> A byte-k pairs with B nibble-k canonically.
//   + concurrent transT(w2) in blocks >= 1280 (R12-proven tail fill).
__global__ __launch_bounds__(256, 2)
void gemm13t_k(const unsigned char* __restrict__ A0, const unsigned char* __restrict__ B1T,
               const unsigned char* __restrict__ B3T, unsigned char* __restrict__ H,
               const int* __restrict__ mcount,
               const float* __restrict__ w2, unsigned char* __restrict__ wT2) {
  __shared__ __align__(16) char smem[48 * 1024];
  if (blockIdx.x >= 1280) {
    int rem = blockIdx.x - 1280;
    int e = rem >> 10, t = rem & 1023;
    transT_tile(w2, wT2, e, (t & 31) * 64, (t >> 5) * 64, smem);
    return;
  }
  int lbid = blockIdx.x;
  int nb = (lbid & 7) * 160 + (lbid >> 3);
  int e = nb / 160, rem = nb % 160, mt = rem >> 4, nt = rem & 15;
  int mc = mcount[e];
  if (mt * 128 >= mc) return;

  char* lA  = smem;                   // 16KB: 128 rows x 128B fp8 (K=128)
  char* lB1 = smem + 16384;           // 16KB: 128 rows x 128B fp4 (K=256)
  char* lB3 = smem + 32768;

  int row0 = e * CAP + mt * 128;
  const unsigned char* gA  = A0 + (size_t)row0 * DM;
  size_t boff = ((size_t)e * DM + (size_t)nt * 128) * KB4;
  const unsigned char* gB1 = B1T + boff;
  const unsigned char* gB3 = B3T + boff;

  int tid = threadIdx.x, w = tid >> 6, l = tid & 63;
  int wr = w >> 1, wc = w & 1;
  int lr = l & 15, kg = l >> 4;

  int sr = tid >> 3;
  int scs = (tid & 7) ^ (sr & 7);

  f32x4 acc1[4][4], acc3[4][4];
#pragma unroll
  for (int m = 0; m < 4; ++m)
#pragma unroll
    for (int n = 0; n < 4; ++n)
#pragma unroll
      for (int j = 0; j < 4; ++j) { acc1[m][n][j] = 0.f; acc3[m][n][j] = 0.f; }

  auto rdA = [&](int R) -> i32x8 {            // fp8: 2 x b128
    int r = R + lr;
    i32x4 lo = *(const i32x4*)(lA + r * 128 + (((2 * kg + 0) ^ (r & 7)) << 4));
    i32x4 hi = *(const i32x4*)(lA + r * 128 + (((2 * kg + 1) ^ (r & 7)) << 4));
    i32x8 v;
    v[0] = lo[0]; v[1] = lo[1]; v[2] = lo[2]; v[3] = lo[3];
    v[4] = hi[0]; v[5] = hi[1]; v[6] = hi[2]; v[7] = hi[3];
    return v;
  };
  auto rdB4 = [&](const char* lX, int R, int half) -> i32x4 {  // fp4: 1 b128
    int r = R + lr;
    int c = half * 4 + kg;
    return *(const i32x4*)(lX + r * 128 + ((c ^ (r & 7)) << 4));
  };
  auto mk8 = [](i32x4 d) -> i32x8 {
    i32x8 v;
    v[0] = d[0]; v[1] = d[1]; v[2] = d[2]; v[3] = d[3];
    v[4] = 0; v[5] = 0; v[6] = 0; v[7] = 0;
    return v;
  };

#pragma unroll 1
  for (int ks = 0; ks < 16; ++ks) {          // K = 2048 = 16 * 128
    // ---- stage A every ks (16KB); B every other ks (16KB each, 2 K-steps)
#pragma unroll
    for (int s = 0; s < 4; ++s) {
      gld16(gA + (size_t)(s * 32 + sr) * DM + (size_t)ks * 128 + scs * 16,
            lA + s * 4096 + w * 1024);
    }
    if ((ks & 1) == 0) {
      size_t t4 = (size_t)(ks >> 1) * 128;
#pragma unroll
      for (int s = 0; s < 4; ++s) {
        size_t goff = (size_t)(s * 32 + sr) * KB4 + t4 + scs * 16;
        gld16(gB1 + goff, lB1 + s * 4096 + w * 1024);
        gld16(gB3 + goff, lB3 + s * 4096 + w * 1024);
      }
    }
    __syncthreads();
    int half = ks & 1;
    i32x4 bf1[4], bf3[4];
#pragma unroll
    for (int n = 0; n < 4; ++n) bf1[n] = rdB4(lB1, wc * 64 + n * 16, half);
#pragma unroll
    for (int n = 0; n < 4; ++n) bf3[n] = rdB4(lB3, wc * 64 + n * 16, half);
#pragma unroll
    for (int m = 0; m < 4; ++m) {
      i32x8 af = rdA(wr * 64 + m * 16);
#pragma unroll
      for (int n = 0; n < 4; ++n)
        acc1[m][n] = __builtin_amdgcn_mfma_scale_f32_16x16x128_f8f6f4(
            af, mk8(bf1[n]), acc1[m][n], 0, 4, 0, 0x7F, 0, 0x7F);
#pragma unroll
      for (int n = 0; n < 4; ++n)
        acc3[m][n] = __builtin_amdgcn_mfma_scale_f32_16x16x128_f8f6f4(
            af, mk8(bf3[n]), acc3[m][n], 0, 4, 0, 0x7F, 0, 0x7F);
    }
    __syncthreads();
  }

  // ---- epilogue: u,v = acc/64; h = fp8(silu(u)*v). m89 C/D layout.
  int rg = l >> 4;
#pragma unroll
  for (int m = 0; m < 4; ++m)
#pragma unroll
    for (int n = 0; n < 4; ++n)
#pragma unroll
      for (int j = 0; j < 4; ++j) {
        int rr = row0 + wr * 64 + m * 16 + rg * 4 + j;
        int cc = nt * 128 + wc * 64 + n * 16 + lr;
        float u = acc1[m][n][j] * INV64;
        float v = acc3[m][n][j] * INV64;
        float s = u / (1.f + __expf(-u));
        H[(size_t)rr * DM + cc] = fp8one(s * v);
      }
}

// ------------------------------------------- ye GEMM: A=h fp8, B=w2 fp4
__global__ __launch_bounds__(256, 4)
void gemm_k(const unsigned char* __restrict__ A0, const unsigned char* __restrict__ BT,
            __bf16* __restrict__ C, const int* __restrict__ mcount) {
  int lbid = blockIdx.x + 16 * (blockIdx.y + 10 * blockIdx.z);
  int nb = (lbid & 7) * 160 + (lbid >> 3);
  int e = nb / 160, rem = nb % 160, mt = rem >> 4, nt = rem & 15;
  int mc = mcount[e];
  if (mt * 128 >= mc) return;

  __shared__ __align__(16) char smem[32 * 1024];
  char* lA = smem;                    // 16KB fp8
  char* lB = smem + 16384;            // 16KB fp4 (2 K-steps)

  int row0 = e * CAP + mt * 128;
  const unsigned char* gA = A0 + (size_t)row0 * DM;
  const unsigned char* gB = BT + ((size_t)e * DM + (size_t)nt * 128) * KB4;

  int tid = threadIdx.x, w = tid >> 6, l = tid & 63;
  int wr = w >> 1, wc = w & 1;
  int lr = l & 15, kg = l >> 4;

  int sr = tid >> 3;
  int scs = (tid & 7) ^ (sr & 7);

  f32x4 acc[4][4];
#pragma unroll
  for (int m = 0; m < 4; ++m)
#pragma unroll
    for (int n = 0; n < 4; ++n)
#pragma unroll
      for (int j = 0; j < 4; ++j) acc[m][n][j] = 0.f;

  auto rdA = [&](int R) -> i32x8 {
    int r = R + lr;
    i32x4 lo = *(const i32x4*)(lA + r * 128 + (((2 * kg + 0) ^ (r & 7)) << 4));
    i32x4 hi = *(const i32x4*)(lA + r * 128 + (((2 * kg + 1) ^ (r & 7)) << 4));
    i32x8 v;
    v[0] = lo[0]; v[1] = lo[1]; v[2] = lo[2]; v[3] = lo[3];
    v[4] = hi[0]; v[5] = hi[1]; v[6] = hi[2]; v[7] = hi[3];
    return v;
  };
  auto rdB4 = [&](int R, int half) -> i32x4 {
    int r = R + lr;
    int c = half * 4 + kg;
    return *(const i32x4*)(lB + r * 128 + ((c ^ (r & 7)) << 4));
  };
  auto mk8 = [](i32x4 d) -> i32x8 {
    i32x8 v;
    v[0] = d[0]; v[1] = d[1]; v[2] = d[2]; v[3] = d[3];
    v[4] = 0; v[5] = 0; v[6] = 0; v[7] = 0;
    return v;
  };

#pragma unroll 1
  for (int ks = 0; ks < 16; ++ks) {
#pragma unroll
    for (int s = 0; s < 4; ++s) {
      gld16(gA + (size_t)(s * 32 + sr) * DM + (size_t)ks * 128 + scs * 16,
            lA + s * 4096 + w * 1024);
    }
    if ((ks & 1) == 0) {
      size_t t4 = (size_t)(ks >> 1) * 128;
#pragma unroll
      for (int s = 0; s < 4; ++s)
        gld16(gB + (size_t)(s * 32 + sr) * KB4 + t4 + scs * 16,
              lB + s * 4096 + w * 1024);
    }
    __syncthreads();
    int half = ks & 1;
    i32x4 bf[4];
#pragma unroll
    for (int n = 0; n < 4; ++n) bf[n] = rdB4(wc * 64 + n * 16, half);
#pragma unroll
    for (int m = 0; m < 4; ++m) {
      i32x8 af = rdA(wr * 64 + m * 16);
#pragma unroll
      for (int n = 0; n < 4; ++n)
        acc[m][n] = __builtin_amdgcn_mfma_scale_f32_16x16x128_f8f6f4(
            af, mk8(bf[n]), acc[m][n], 0, 4, 0, 0x7F, 0, 0x7F);
    }
    __syncthreads();
  }

  int rg = l >> 4;
#pragma unroll
  for (int m = 0; m < 4; ++m)
#pragma unroll
    for (int n = 0; n < 4; ++n)
#pragma unroll
      for (int j = 0; j < 4; ++j) {
        int rr = row0 + wr * 64 + m * 16 + rg * 4 + j;
        int cc = nt * 128 + wc * 64 + n * 16 + lr;
        C[(size_t)rr * DM + cc] = (__bf16)(acc[m][n][j] * INV64);
      }
}

// --------------------------------------------- combine: y[tok] = sum w * ye
__global__ void combine_k(const __bf16* __restrict__ ye, const int* __restrict__ slot_dest,
                          const float* __restrict__ ew, float* __restrict__ out) {
  int tok = blockIdx.x;
  int c = threadIdx.x * 8;
  int d0 = slot_dest[2 * tok], d1 = slot_dest[2 * tok + 1];
  float w0 = ew[2 * tok], w1 = ew[2 * tok + 1];
  float r[8];
#pragma unroll
  for (int j = 0; j < 8; ++j) r[j] = 0.f;
  if (d0 >= 0) {
    bf16x8 y0 = *(const bf16x8*)(ye + (size_t)d0 * DM + c);
#pragma unroll
    for (int j = 0; j < 8; ++j) r[j] += w0 * (float)y0[j];
  }
  if (d1 >= 0) {
    bf16x8 y1 = *(const bf16x8*)(ye + (size_t)d1 * DM + c);
#pragma unroll
    for (int j = 0; j < 8; ++j) r[j] += w1 * (float)y1[j];
  }
  float* dst = out + (size_t)tok * DM + c;
  float4 o0; o0.x = r[0]; o0.y = r[1]; o0.z = r[2]; o0.w = r[3];
  float4 o1; o1.x = r[4]; o1.y = r[5]; o1.z = r[6]; o1.w = r[7];
  *(float4*)dst = o0;
  *(float4*)(dst + 4) = o1;
}

extern "C" void kernel_launch(void* const* d_in, const int* in_sizes, int n_in,
                              void* d_out, int out_size, void* d_ws, size_t ws_size,
                              hipStream_t stream) {
  const float* x  = (const float*)d_in[0];
  const float* ew = (const float*)d_in[1];
  const int*   ei = (const int*)d_in[2];
  const float* w1 = (const float*)d_in[3];
  const float* w2 = (const float*)d_in[4];
  const float* w3 = (const float*)d_in[5];
  float* out = (float*)d_out;
  char* ws = (char*)d_ws;

  // ws: xg fp8 21MB | yeB bf16 42MB | hB fp8 21MB | wT1/wT3/wT2 fp4 16.8MB
  //     each | routing ints   (~135MB total)
  const size_t SZ8  = (size_t)EC * DM;                  // 20,971,520
  const size_t SZ16 = 2 * SZ8;
  const size_t SZW4 = (size_t)NEXP * DM * KB4;          // 16,777,216
  unsigned char* xg  = (unsigned char*)ws;
  __bf16* yeB        = (__bf16*)(ws + SZ8);
  unsigned char* hB  = (unsigned char*)(ws + SZ8 + SZ16);
  unsigned char* wT1 = (unsigned char*)(ws + 2 * SZ8 + SZ16);
  unsigned char* wT3 = (unsigned char*)(ws + 2 * SZ8 + SZ16 + SZW4);
  unsigned char* wT2 = (unsigned char*)(ws + 2 * SZ8 + SZ16 + 2 * SZW4);
  char* ints = ws + 2 * SZ8 + SZ16 + 3 * SZW4;
  int* row_token = (int*)ints;
  int* slot_dest = row_token + EC;
  int* mcount    = slot_dest + NSLOT;

  dim3 ggrid(16, 10, NEXP);

  route_k<<<1, 256, 0, stream>>>(ei, row_token, slot_dest, mcount, out);
  prep_k<<<17664, 256, 0, stream>>>(w1, w3, wT1, wT3, x, row_token, xg);
  gemm13t_k<<<9472, 256, 0, stream>>>(xg, wT1, wT3, hB, mcount, w2, wT2);
  gemm_k<<<ggrid, 256, 0, stream>>>(hB, wT2, yeB, mcount);
  combine_k<<<NTOK, 256, 0, stream>>>(yeB, slot_dest, ew, out);
}

// Round 14
// 265.764 us; speedup vs baseline: 1.0049x; 1.0049x over previous
//
#include <hip/hip_runtime.h>
#include <cstdint>

#define NEXP 8
#define TOPK 2
#define NTOK 4096
#define NSLOT (NTOK * TOPK)   // 8192
#define CAP 1280              // expert capacity
#define DM 2048               // d_model == hidden
#define EC (NEXP * CAP)       // 10240 binned rows

typedef __bf16 bf16x8 __attribute__((ext_vector_type(8)));
typedef float  f32x4  __attribute__((ext_vector_type(4)));
typedef int    i32x4  __attribute__((ext_vector_type(4)));
typedef int    i32x8  __attribute__((ext_vector_type(8)));

typedef const void __attribute__((address_space(1))) gvoid;
typedef void __attribute__((address_space(3))) lvoid;

__device__ __forceinline__ void gld16(const void* g, void* l) {
  __builtin_amdgcn_global_load_lds((gvoid*)(uintptr_t)g, (lvoid*)(uintptr_t)l,
                                   16, 0, 0);
}

// pack 4 f32 -> 4 fp8 e4m3 bytes (OCP on gfx950)
__device__ __forceinline__ unsigned fp8x4(float a, float b, float c, float d) {
  int v = __builtin_amdgcn_cvt_pk_fp8_f32(a, b, 0, false);
  v = __builtin_amdgcn_cvt_pk_fp8_f32(c, d, v, true);
  return (unsigned)v;
}
__device__ __forceinline__ unsigned char fp8one(float a) {
  return (unsigned char)(__builtin_amdgcn_cvt_pk_fp8_f32(a, a, 0, false) & 0xff);
}

// ---------------------------------------------------------------- routing
__global__ void route_k(const int* __restrict__ eidx, int* __restrict__ row_token,
                        int* __restrict__ slot_dest, int* __restrict__ mcount,
                        float* __restrict__ out) {
  __shared__ int lh[256][NEXP];
  int tid = threadIdx.x;
  for (int i = tid; i < EC; i += 256) row_token[i] = -1;
#pragma unroll
  for (int e = 0; e < NEXP; ++e) lh[tid][e] = 0;
  __syncthreads();
  int base = tid * 32;
  for (int j = 0; j < 32; ++j) lh[tid][eidx[base + j]]++;
  __syncthreads();
  if (tid < NEXP) {
    int run = 0;
    for (int i = 0; i < 256; ++i) { int t = lh[i][tid]; lh[i][tid] = run; run += t; }
    mcount[tid] = run < CAP ? run : CAP;
    out[(size_t)NTOK * DM + tid] = (float)run;
  }
  __syncthreads();
  for (int j = 0; j < 32; ++j) {
    int t = base + j;
    int e = eidx[t];
    int r = lh[tid][e]++;
    if (r < CAP) { int dst = e * CAP + r; slot_dest[t] = dst; row_token[dst] = t >> 1; }
    else slot_dest[t] = -1;
  }
}

// ---------------------- device body: one 64x64 fp32->fp8 transpose tile
__device__ __forceinline__ void transT_tile(const float* __restrict__ w,
                                            unsigned char* __restrict__ wT,
                                            int e, int n0, int k0, char* smem) {
  float (*t)[69] = (float (*)[69])smem;
  const float* src = w + ((size_t)e << 22) + (size_t)k0 * DM + n0;
  unsigned char* dst = wT + ((size_t)e << 22) + (size_t)n0 * DM + k0;
  int c4 = (threadIdx.x & 15) * 4, r0 = threadIdx.x >> 4;   // 16 rows/sweep
#pragma unroll
  for (int p = 0; p < 4; ++p) {
    int r = p * 16 + r0;
    float4 v = *(const float4*)(src + (size_t)r * DM + c4);
    t[r][c4 + 0] = v.x; t[r][c4 + 1] = v.y; t[r][c4 + 2] = v.z; t[r][c4 + 3] = v.w;
  }
  __syncthreads();
  int j = threadIdx.x & 7, rr0 = threadIdx.x >> 3;          // 32 rows/sweep
#pragma unroll
  for (int q = 0; q < 2; ++q) {
    int rr = q * 32 + rr0;
    int k8 = j * 8;
    uint2 v;
    v.x = fp8x4(t[k8 + 0][rr], t[k8 + 1][rr], t[k8 + 2][rr], t[k8 + 3][rr]);
    v.y = fp8x4(t[k8 + 4][rr], t[k8 + 5][rr], t[k8 + 6][rr], t[k8 + 7][rr]);
    *(uint2*)(dst + (size_t)rr * DM + k8) = v;              // 8B stores
  }
}

// ------------- prep: transT(w1) + transT(w3) + gather, one HBM-bound launch
// blocks 0..8191: w1 tiles; 8192..16383: w3 tiles; 16384..17663: gather x8 rows
__global__ __launch_bounds__(256)
void prep_k(const float* __restrict__ w1, const float* __restrict__ w3,
            unsigned char* __restrict__ wT1, unsigned char* __restrict__ wT3,
            const float* __restrict__ x, const int* __restrict__ row_token,
            unsigned char* __restrict__ xg) {
  __shared__ __align__(16) char smem[64 * 69 * 4];
  int bid = blockIdx.x;
  if (bid < 16384) {
    const float* w = (bid & 8192) ? w3 : w1;
    unsigned char* wT = (bid & 8192) ? wT3 : wT1;
    int rem = bid & 8191;
    int e = rem >> 10, t = rem & 1023;
    transT_tile(w, wT, e, (t & 31) * 64, (t >> 5) * 64, smem);
  } else {
    int rbase = (bid - 16384) * 8;
    int c = threadIdx.x * 8;
#pragma unroll 1
    for (int i = 0; i < 8; ++i) {
      int r = rbase + i;
      int tok = row_token[r];
      uint2 o;
      if (tok >= 0) {
        const float* src = x + (size_t)tok * DM + c;
        float4 a = *(const float4*)src;
        float4 b = *(const float4*)(src + 4);
        o.x = fp8x4(a.x, a.y, a.z, a.w);
        o.y = fp8x4(b.x, b.y, b.z, b.w);
      } else { o.x = 0u; o.y = 0u; }
      *(uint2*)(xg + (size_t)r * DM + c) = o;
    }
  }
}

// ---------------------------------------------- fused SwiGLU dual-B GEMM
//   + concurrent transT(w2): blocks 0..1279 gemm13 (dispatched first),
//   1280..9471 transT w2 tiles (fill CU slots as gemm13 retires; gemm13 is
//   ~10% HBM so the HBM-bound transpose hides under it). Block-uniform
//   branch; LDS 48KB static (transT uses first 17.7KB).
// gemm13: h = fp8( silu(xg@w1T) * (xg@w3T) ) — R11-proven (128x128, BK=128,
// 4 waves, single-buffer 2-barrier loop, mfma_scale_f32_16x16x128 unit
// scales, dual acc, swizzle rule #21, m89 epilogue, XCD-chunked swizzle).
__global__ __launch_bounds__(256, 2)
void gemm13t_k(const unsigned char* __restrict__ A0, const unsigned char* __restrict__ B1T,
               const unsigned char* __restrict__ B3T, unsigned char* __restrict__ H,
               const int* __restrict__ mcount,
               const float* __restrict__ w2, unsigned char* __restrict__ wT2) {
  __shared__ __align__(16) char smem[48 * 1024];
  if (blockIdx.x >= 1280) {
    int rem = blockIdx.x - 1280;
    int e = rem >> 10, t = rem & 1023;
    transT_tile(w2, wT2, e, (t & 31) * 64, (t >> 5) * 64, smem);
    return;
  }
  int lbid = blockIdx.x;
  int nb = (lbid & 7) * 160 + (lbid >> 3);
  int e = nb / 160, rem = nb % 160, mt = rem >> 4, nt = rem & 15;
  int mc = mcount[e];
  if (mt * 128 >= mc) return;

  char* lA  = smem;
  char* lB1 = smem + 16384;
  char* lB3 = smem + 32768;

  int row0 = e * CAP + mt * 128;
  const unsigned char* gA  = A0 + (size_t)row0 * DM;
  size_t boff = ((size_t)e * DM + (size_t)nt * 128) * DM;
  const unsigned char* gB1 = B1T + boff;
  const unsigned char* gB3 = B3T + boff;

  int tid = threadIdx.x, w = tid >> 6, l = tid & 63;
  int wr = w >> 1, wc = w & 1;
  int lr = l & 15, kg = l >> 4;

  int sr = tid >> 3;
  int scs = (tid & 7) ^ (sr & 7);

  f32x4 acc1[4][4], acc3[4][4];
#pragma unroll
  for (int m = 0; m < 4; ++m)
#pragma unroll
    for (int n = 0; n < 4; ++n)
#pragma unroll
      for (int j = 0; j < 4; ++j) { acc1[m][n][j] = 0.f; acc3[m][n][j] = 0.f; }

  auto rdfrag = [&](const char* lX, int R) -> i32x8 {
    int r = R + lr;
    int a0 = r * 128 + (((2 * kg + 0) ^ (r & 7)) << 4);
    int a1 = r * 128 + (((2 * kg + 1) ^ (r & 7)) << 4);
    i32x4 lo = *(const i32x4*)(lX + a0);
    i32x4 hi = *(const i32x4*)(lX + a1);
    i32x8 v;
    v[0] = lo[0]; v[1] = lo[1]; v[2] = lo[2]; v[3] = lo[3];
    v[4] = hi[0]; v[5] = hi[1]; v[6] = hi[2]; v[7] = hi[3];
    return v;
  };

#pragma unroll 1
  for (int ks = 0; ks < 16; ++ks) {          // K = 2048 = 16 * 128
#pragma unroll
    for (int s = 0; s < 4; ++s) {
      size_t goff = (size_t)(s * 32 + sr) * DM + (size_t)ks * 128 + scs * 16;
      gld16(gA  + goff, lA  + s * 4096 + w * 1024);
      gld16(gB1 + goff, lB1 + s * 4096 + w * 1024);
      gld16(gB3 + goff, lB3 + s * 4096 + w * 1024);
    }
    __syncthreads();
    i32x8 bf1[4], bf3[4];
#pragma unroll
    for (int n = 0; n < 4; ++n) bf1[n] = rdfrag(lB1, wc * 64 + n * 16);
#pragma unroll
    for (int n = 0; n < 4; ++n) bf3[n] = rdfrag(lB3, wc * 64 + n * 16);
#pragma unroll
    for (int m = 0; m < 4; ++m) {
      i32x8 af = rdfrag(lA, wr * 64 + m * 16);
#pragma unroll
      for (int n = 0; n < 4; ++n)
        acc1[m][n] = __builtin_amdgcn_mfma_scale_f32_16x16x128_f8f6f4(
            af, bf1[n], acc1[m][n], 0, 0, 0, 0x7F, 0, 0x7F);
#pragma unroll
      for (int n = 0; n < 4; ++n)
        acc3[m][n] = __builtin_amdgcn_mfma_scale_f32_16x16x128_f8f6f4(
            af, bf3[n], acc3[m][n], 0, 0, 0, 0x7F, 0, 0x7F);
    }
    __syncthreads();
  }

  int rg = l >> 4;
#pragma unroll
  for (int m = 0; m < 4; ++m)
#pragma unroll
    for (int n = 0; n < 4; ++n)
#pragma unroll
      for (int j = 0; j < 4; ++j) {
        int rr = row0 + wr * 64 + m * 16 + rg * 4 + j;
        int cc = nt * 128 + wc * 64 + n * 16 + lr;
        float u = acc1[m][n][j];
        float s = u / (1.f + __expf(-u));
        H[(size_t)rr * DM + cc] = fp8one(s * acc3[m][n][j]);
      }
}

// ------------------------------------------------------------------- GEMM
// R10-proven single-B MX-fp8 GEMM (ye pass): 128x128, BK=128, 32KB LDS.
__global__ __launch_bounds__(256, 4)
void gemm_k(const unsigned char* __restrict__ A0, const unsigned char* __restrict__ BT,
            __bf16* __restrict__ C, const int* __restrict__ mcount) {
  int lbid = blockIdx.x + 16 * (blockIdx.y + 10 * blockIdx.z);
  int nb = (lbid & 7) * 160 + (lbid >> 3);
  int e = nb / 160, rem = nb % 160, mt = rem >> 4, nt = rem & 15;
  int mc = mcount[e];
  if (mt * 128 >= mc) return;

  __shared__ __align__(16) char smem[32 * 1024];
  char* lA = smem;
  char* lB = smem + 16384;

  int row0 = e * CAP + mt * 128;
  const unsigned char* gA = A0 + (size_t)row0 * DM;
  const unsigned char* gB = BT + ((size_t)e * DM + (size_t)nt * 128) * DM;

  int tid = threadIdx.x, w = tid >> 6, l = tid & 63;
  int wr = w >> 1, wc = w & 1;
  int lr = l & 15, kg = l >> 4;

  int sr = tid >> 3;
  int scs = (tid & 7) ^ (sr & 7);

  f32x4 acc[4][4];
#pragma unroll
  for (int m = 0; m < 4; ++m)
#pragma unroll
    for (int n = 0; n < 4; ++n)
#pragma unroll
      for (int j = 0; j < 4; ++j) acc[m][n][j] = 0.f;

  auto rdfrag = [&](const char* lX, int R) -> i32x8 {
    int r = R + lr;
    int a0 = r * 128 + (((2 * kg + 0) ^ (r & 7)) << 4);
    int a1 = r * 128 + (((2 * kg + 1) ^ (r & 7)) << 4);
    i32x4 lo = *(const i32x4*)(lX + a0);
    i32x4 hi = *(const i32x4*)(lX + a1);
    i32x8 v;
    v[0] = lo[0]; v[1] = lo[1]; v[2] = lo[2]; v[3] = lo[3];
    v[4] = hi[0]; v[5] = hi[1]; v[6] = hi[2]; v[7] = hi[3];
    return v;
  };

#pragma unroll 1
  for (int ks = 0; ks < 16; ++ks) {          // K = 2048 = 16 * 128
#pragma unroll
    for (int s = 0; s < 4; ++s) {
      size_t goff = (size_t)(s * 32 + sr) * DM + (size_t)ks * 128 + scs * 16;
      gld16(gA + goff, lA + s * 4096 + w * 1024);
      gld16(gB + goff, lB + s * 4096 + w * 1024);
    }
    __syncthreads();
    i32x8 bf[4];
#pragma unroll
    for (int n = 0; n < 4; ++n) bf[n] = rdfrag(lB, wc * 64 + n * 16);
#pragma unroll
    for (int m = 0; m < 4; ++m) {
      i32x8 af = rdfrag(lA, wr * 64 + m * 16);
#pragma unroll
      for (int n = 0; n < 4; ++n)
        acc[m][n] = __builtin_amdgcn_mfma_scale_f32_16x16x128_f8f6f4(
            af, bf[n], acc[m][n], 0, 0, 0, 0x7F, 0, 0x7F);
    }
    __syncthreads();
  }

  int rg = l >> 4;
#pragma unroll
  for (int m = 0; m < 4; ++m)
#pragma unroll
    for (int n = 0; n < 4; ++n)
#pragma unroll
      for (int j = 0; j < 4; ++j) {
        int rr = row0 + wr * 64 + m * 16 + rg * 4 + j;
        int cc = nt * 128 + wc * 64 + n * 16 + lr;
        C[(size_t)rr * DM + cc] = (__bf16)acc[m][n][j];
      }
}

// --------------------------------------------- combine: y[tok] = sum w * ye
__global__ void combine_k(const __bf16* __restrict__ ye, const int* __restrict__ slot_dest,
                          const float* __restrict__ ew, float* __restrict__ out) {
  int tok = blockIdx.x;
  int c = threadIdx.x * 8;
  int d0 = slot_dest[2 * tok], d1 = slot_dest[2 * tok + 1];
  float w0 = ew[2 * tok], w1 = ew[2 * tok + 1];
  float r[8];
#pragma unroll
  for (int j = 0; j < 8; ++j) r[j] = 0.f;
  if (d0 >= 0) {
    bf16x8 y0 = *(const bf16x8*)(ye + (size_t)d0 * DM + c);
#pragma unroll
    for (int j = 0; j < 8; ++j) r[j] += w0 * (float)y0[j];
  }
  if (d1 >= 0) {
    bf16x8 y1 = *(const bf16x8*)(ye + (size_t)d1 * DM + c);
#pragma unroll
    for (int j = 0; j < 8; ++j) r[j] += w1 * (float)y1[j];
  }
  float* dst = out + (size_t)tok * DM + c;
  float4 o0; o0.x = r[0]; o0.y = r[1]; o0.z = r[2]; o0.w = r[3];
  float4 o1; o1.x = r[4]; o1.y = r[5]; o1.z = r[6]; o1.w = r[7];
  *(float4*)dst = o0;
  *(float4*)(dst + 4) = o1;
}

extern "C" void kernel_launch(void* const* d_in, const int* in_sizes, int n_in,
                              void* d_out, int out_size, void* d_ws, size_t ws_size,
                              hipStream_t stream) {
  const float* x  = (const float*)d_in[0];
  const float* ew = (const float*)d_in[1];
  const int*   ei = (const int*)d_in[2];
  const float* w1 = (const float*)d_in[3];
  const float* w2 = (const float*)d_in[4];
  const float* w3 = (const float*)d_in[5];
  float* out = (float*)d_out;
  char* ws = (char*)d_ws;

  // ws: xg fp8 21MB | yeB bf16 42MB | hB fp8 21MB | wT1 | wT3 | wT2 (33.5MB
  //     each) | routing ints   (~185MB total)
  const size_t SZ8  = (size_t)EC * DM;                  // 20,971,520
  const size_t SZ16 = 2 * SZ8;
  const size_t SZW  = (size_t)NEXP * DM * DM;           // 33,554,432
  unsigned char* xg  = (unsigned char*)ws;
  __bf16* yeB        = (__bf16*)(ws + SZ8);
  unsigned char* hB  = (unsigned char*)(ws + SZ8 + SZ16);
  unsigned char* wT1 = (unsigned char*)(ws + 2 * SZ8 + SZ16);
  unsigned char* wT3 = (unsigned char*)(ws + 2 * SZ8 + SZ16 + SZW);
  unsigned char* wT2 = (unsigned char*)(ws + 2 * SZ8 + SZ16 + 2 * SZW);
  char* ints = ws + 2 * SZ8 + SZ16 + 3 * SZW;
  int* row_token = (int*)ints;
  int* slot_dest = row_token + EC;
  int* mcount    = slot_dest + NSLOT;

  dim3 ggrid(16, 10, NEXP);                             // ye gemm grid

  route_k<<<1, 256, 0, stream>>>(ei, row_token, slot_dest, mcount, out);
  prep_k<<<17664, 256, 0, stream>>>(w1, w3, wT1, wT3, x, row_token, xg);
  gemm13t_k<<<9472, 256, 0, stream>>>(xg, wT1, wT3, hB, mcount, w2, wT2); // h + w2 prep
  gemm_k<<<ggrid, 256, 0, stream>>>(hB, wT2, yeB, mcount);                // ye (bf16)
  combine_k<<<NTOK, 256, 0, stream>>>(yeB, slot_dest, ew, out);
}